// Round 7
// baseline (250.857 us; speedup 1.0000x reference)
//
#include <hip/hip_runtime.h>
#include <stdint.h>
#include <math.h>

// Problem constants
constexpr int T_ = 4;
constexpr int B_ = 8;
constexpr int C_ = 256;
constexpr int N_ = 256;          // H*W
constexpr int TN_ = 1024;        // T*N
constexpr int NH_ = 8;           // heads
constexpr int O3_ = 768;         // 3*C
constexpr int BIAS_ROWS_ = 6727; // 7*31*31

__device__ __constant__ int TI_OF[10] = {0,1,1,2,2,2,3,3,3,3};
__device__ __constant__ int TJ_OF[10] = {0,0,1,0,1,2,0,1,2,3};

__device__ __forceinline__ float quant1f(float m) {
    return rintf(fminf(fmaxf(m, 0.0f), 1.0f));
}

// ---------------------------------------------------------------------------
// K1: qkv = BN(w_qkv @ xf)   out[b][o][l]
// 96(M) x 256(N) tile, 256 threads, 12x8 microtile, K-chunk 16.
// 2.4 FLOP per LDS byte (vs 1.33 in R6's 8x4) -- R6 was LDS-throughput-bound.
// Grid 4x8x8 = 256 blocks = 1/CU. Ascending-k accumulation (bit-identical).
// ---------------------------------------------------------------------------
__global__ __launch_bounds__(256, 1) void k1_qkv_gemm(
    const float* __restrict__ x, const float* __restrict__ w,
    const float* __restrict__ gamma, const float* __restrict__ beta,
    const float* __restrict__ mean, const float* __restrict__ var,
    float* __restrict__ out)
{
    __shared__ float At[16][100];  // [k][m], m=96 (+4 pad)
    __shared__ float Bt[16][264];  // [k][n], n=256 (+8 pad)
    const int b = blockIdx.z;
    const int oBase = blockIdx.y * 96;
    const int lBase = blockIdx.x * 256;
    const int tid = threadIdx.x;
    const int tx = tid & 31;        // n: cols tx*8..+7
    const int ty = tid >> 5;        // m: rows {0,32,64}+ty*4..+3
    const float* xb = x + (size_t)b * C_ * TN_;

    float acc[12][8];
#pragma unroll
    for (int i = 0; i < 12; ++i)
#pragma unroll
        for (int j = 0; j < 8; ++j) acc[i][j] = 0.0f;

    const int a_row = tid >> 3, a_k2 = (tid & 7) * 2;
    const int b_kk = tid >> 4, b_c16 = (tid & 15) * 16;

    for (int kc = 0; kc < 16; ++kc) {
        const int k0 = kc * 16;
        // A: 96 rows x 16 k as float2 x3/thread, store transposed
#pragma unroll
        for (int r = 0; r < 3; ++r) {
            const int row = a_row + 32 * r;
            const float2 v = *(const float2*)&w[(size_t)(oBase + row) * C_ + k0 + a_k2];
            At[a_k2][row] = v.x;
            At[a_k2 + 1][row] = v.y;
        }
        // B: 16 k x 256 l, 4 float4/thread coalesced
#pragma unroll
        for (int r = 0; r < 4; ++r) {
            const float4 v = *(const float4*)&xb[(size_t)(k0 + b_kk) * TN_ + lBase + b_c16 + 4 * r];
            *(float4*)&Bt[b_kk][b_c16 + 4 * r] = v;
        }
        __syncthreads();
#pragma unroll
        for (int cc = 0; cc < 16; ++cc) {
            float a[12], bb[8];
            *(float4*)&a[0] = *(const float4*)&At[cc][ty * 4];
            *(float4*)&a[4] = *(const float4*)&At[cc][32 + ty * 4];
            *(float4*)&a[8] = *(const float4*)&At[cc][64 + ty * 4];
            *(float4*)&bb[0] = *(const float4*)&Bt[cc][tx * 8];
            *(float4*)&bb[4] = *(const float4*)&Bt[cc][tx * 8 + 4];
#pragma unroll
            for (int i = 0; i < 12; ++i)
#pragma unroll
                for (int j = 0; j < 8; ++j) acc[i][j] += a[i] * bb[j];
        }
        __syncthreads();
    }

#pragma unroll
    for (int i = 0; i < 12; ++i) {
        const int o = oBase + (i >> 2) * 32 + ty * 4 + (i & 3);
        const float inv = 1.0f / sqrtf(var[o] + 1e-5f);
        const float g = gamma[o] * inv;
        const float mn = mean[o], bt = beta[o];
        float4 s0, s1;
        s0.x = (acc[i][0] - mn) * g + bt;
        s0.y = (acc[i][1] - mn) * g + bt;
        s0.z = (acc[i][2] - mn) * g + bt;
        s0.w = (acc[i][3] - mn) * g + bt;
        s1.x = (acc[i][4] - mn) * g + bt;
        s1.y = (acc[i][5] - mn) * g + bt;
        s1.z = (acc[i][6] - mn) * g + bt;
        s1.w = (acc[i][7] - mn) * g + bt;
        float* dst = &out[((size_t)b * O3_ + o) * TN_ + lBase + tx * 8];
        *(float4*)&dst[0] = s0;
        *(float4*)&dst[4] = s1;
    }
}

// ---------------------------------------------------------------------------
// K2: LIF over t on qkv_bn, pack spikes. 2x parallelism vs R6: each thread
// handles 16 d's; lane pairs (same n, dh 0/1) recombine via __shfl_xor.
// Grid (24, 8, 2) = 384 blocks.
// ---------------------------------------------------------------------------
__global__ __launch_bounds__(256) void k2_lif_pack(
    const float* __restrict__ qkv,
    uint32_t* __restrict__ qb, uint32_t* __restrict__ kb, uint32_t* __restrict__ vb)
{
    const int tid = threadIdx.x;
    const int g = blockIdx.x;
    const int b = blockIdx.y;
    const int n = blockIdx.z * 128 + (tid >> 1);
    const int dh = tid & 1;
    const int dbase = dh * 16;
    const int which = g >> 3, h = g & 7;
    uint32_t* dst = (which == 0) ? qb : (which == 1) ? kb : vb;
    const float* src = qkv + ((size_t)b * O3_ + g * 32 + dbase) * TN_;

    float memv[16];
#pragma unroll
    for (int d = 0; d < 16; ++d) memv[d] = 0.0f;
    uint32_t prevFull = 0;

    for (int t = 0; t < T_; ++t) {
        uint32_t bits = 0;
#pragma unroll
        for (int dd = 0; dd < 16; ++dd) {
            const float xv = src[(size_t)dd * TN_ + t * N_ + n];
            const float m = (memv[dd] - 0.5f * (float)((prevFull >> (dbase + dd)) & 1u)) * 0.25f + xv;
            memv[dd] = m;
            const float s = quant1f(m);
            bits |= ((uint32_t)s) << (dbase + dd);
        }
        const uint32_t full = bits | (uint32_t)__shfl_xor((int)bits, 1);
        prevFull = full;
        if (dh == 0)
            dst[((size_t)b * NH_ + h) * TN_ + t * N_ + n] = full;
    }
}

// ---------------------------------------------------------------------------
// K3tg: fused ballot bit-transpose + cumulative Gram matrix, one block per bh.
// ---------------------------------------------------------------------------
__global__ __launch_bounds__(256) void k3_tg(
    const uint32_t* __restrict__ kb, const uint32_t* __restrict__ vb,
    float* __restrict__ Gf)
{
    __shared__ uint64_t ks[4][32][4];
    __shared__ uint64_t vs[4][32][4];
    const int bh = blockIdx.x;
    const int tid = threadIdx.x;
    const int q = tid >> 6, lane = tid & 63;

#pragma unroll
    for (int t = 0; t < T_; ++t) {
        const int j = t * N_ + q * 64 + lane;
        const uint32_t kw = kb[(size_t)bh * TN_ + j];
        const uint32_t vw = vb[(size_t)bh * TN_ + j];
#pragma unroll
        for (int d = 0; d < 32; ++d) {
            const uint64_t mk = __ballot((kw >> d) & 1u);
            const uint64_t mv = __ballot((vw >> d) & 1u);
            if (lane == 0) { ks[t][d][q] = mk; vs[t][d][q] = mv; }
        }
    }
    __syncthreads();

    const int d = tid & 31;
#pragma unroll
    for (int s = 0; s < 4; ++s) {
        const int d2 = (tid >> 5) + 8 * s;
        int cum = 0;
#pragma unroll
        for (int t = 0; t < T_; ++t) {
            int p = 0;
#pragma unroll
            for (int w = 0; w < 4; ++w) p += __popcll(ks[t][d2][w] & vs[t][d][w]);
            cum += p;
            Gf[(size_t)(bh * 4 + t) * 1024 + d2 * 32 + d] = (float)cum;
        }
    }
}

// ---------------------------------------------------------------------------
// K3s1: S1[i,d] = sum_{d2} qbit[i,d2] * G_ti[d2,d] -> oatt (unscaled)
// ---------------------------------------------------------------------------
__global__ __launch_bounds__(256) void k3_s1(
    const uint32_t* __restrict__ qb, const float* __restrict__ Gf,
    float* __restrict__ oatt)
{
    const int grp = blockIdx.x;
    const int ti = grp >> 2, seg = grp & 3;
    const int h = blockIdx.y;
    const int b = blockIdx.z;
    const int bh = b * NH_ + h;
    const int tid = threadIdx.x;
    const int d = tid & 31;
    const int ig = tid >> 5;

    const float* gsrc = Gf + (size_t)(bh * 4 + ti) * 1024 + d;
    float g[32];
#pragma unroll
    for (int d2 = 0; d2 < 32; ++d2) g[d2] = gsrc[d2 * 32];

    const uint32_t* qbh = qb + (size_t)bh * TN_;
    const int i0 = ti * N_ + seg * 64 + ig * 8;
#pragma unroll
    for (int s = 0; s < 8; ++s) {
        const int i = i0 + s;
        const uint32_t q = qbh[i];
        float acc = 0.0f;
#pragma unroll
        for (int d2 = 0; d2 < 32; ++d2)
            acc += ((q >> d2) & 1u) ? g[d2] : 0.0f;
        oatt[((size_t)b * TN_ + i) * C_ + h * 32 + d] = acc;
    }
}

// ---------------------------------------------------------------------------
// K3gemm: balanced split-K bias GEMM (unchanged from R6).
// ---------------------------------------------------------------------------
__global__ __launch_bounds__(256) void k3_bias_gemm(
    const uint32_t* __restrict__ vb, const float* __restrict__ bias_table,
    float* __restrict__ p0, float* __restrict__ p1,
    float* __restrict__ p2, float* __restrict__ p3)
{
    __shared__ float sbl[640];
    __shared__ float At[16][68];
    __shared__ float Bt[16][132];

    const int z = blockIdx.z;
    const int h = z / 10;
    const int p = z % 10;
    const int ti = TI_OF[p], tj = TJ_OF[p];
    const int dt = ti - tj;
    const int iT = blockIdx.y;
    const int nBase = blockIdx.x * 128;
    const int tid = threadIdx.x;

    const int base = 3363 + 961 * dt + 124 * iT - 480;
    for (int s = tid; s < 640; s += 256) {
        const int gidx = base + s;
        sbl[s] = (gidx < BIAS_ROWS_) ? bias_table[(size_t)gidx * NH_ + h] : 0.0f;
    }

    const int ty = tid >> 4, tx = tid & 15;

    const int ccS = tx;
    const int iBase4 = ty * 4;
    const int sIdxBase = 31 * (iBase4 >> 4) + (iBase4 & 15) + 480 - ccS;

    const int kkS = ty;
    const int n8 = tx * 8;
    const int nS = nBase + n8;
    const int bS = nS >> 5, d0S = nS & 31;
    const uint32_t* vbw = vb + ((size_t)bS * NH_ + h) * TN_ + tj * 256 + kkS;

    float acc[4][8];
#pragma unroll
    for (int i = 0; i < 4; ++i)
#pragma unroll
        for (int j = 0; j < 8; ++j) acc[i][j] = 0.0f;

    __syncthreads();

    for (int kc = 0; kc < 16; ++kc) {
        {
            const int s0 = sIdxBase - 31 * kc;
            float4 av;
            av.x = sbl[s0];
            av.y = sbl[s0 + 1];
            av.z = sbl[s0 + 2];
            av.w = sbl[s0 + 3];
            *(float4*)&At[ccS][iBase4] = av;
        }
        {
            const uint32_t wd = vbw[kc * 16];
            float4 b0, b1;
            b0.x = (float)((wd >> d0S) & 1u);
            b0.y = (float)((wd >> (d0S + 1)) & 1u);
            b0.z = (float)((wd >> (d0S + 2)) & 1u);
            b0.w = (float)((wd >> (d0S + 3)) & 1u);
            b1.x = (float)((wd >> (d0S + 4)) & 1u);
            b1.y = (float)((wd >> (d0S + 5)) & 1u);
            b1.z = (float)((wd >> (d0S + 6)) & 1u);
            b1.w = (float)((wd >> (d0S + 7)) & 1u);
            *(float4*)&Bt[kkS][n8] = b0;
            *(float4*)&Bt[kkS][n8 + 4] = b1;
        }
        __syncthreads();
#pragma unroll
        for (int cc = 0; cc < 16; ++cc) {
            float a[4], bb[8];
            *(float4*)&a[0] = *(const float4*)&At[cc][ty * 4];
            *(float4*)&bb[0] = *(const float4*)&Bt[cc][tx * 8];
            *(float4*)&bb[4] = *(const float4*)&Bt[cc][tx * 8 + 4];
#pragma unroll
            for (int i = 0; i < 4; ++i)
#pragma unroll
                for (int j = 0; j < 8; ++j) acc[i][j] += a[i] * bb[j];
        }
        __syncthreads();
    }

    float* plane = (tj == 0) ? p0 : (tj == 1) ? p1 : (tj == 2) ? p2 : p3;
    const int nrows = (4 - tj) * 256;
    const int c0 = h * 32 + d0S;
#pragma unroll
    for (int r = 0; r < 4; ++r) {
        const int rowL = dt * 256 + iT * 64 + ty * 4 + r;
        float* dst = &plane[((size_t)bS * nrows + rowL) * 256 + c0];
        float4 s0, s1;
        s0.x = acc[r][0]; s0.y = acc[r][1]; s0.z = acc[r][2]; s0.w = acc[r][3];
        s1.x = acc[r][4]; s1.y = acc[r][5]; s1.z = acc[r][6]; s1.w = acc[r][7];
        *(float4*)&dst[0] = s0;
        *(float4*)&dst[4] = s1;
    }
}

// ---------------------------------------------------------------------------
// K4: combine S1 + bias partials, scale 0.125, LIF over t -> bit-packed spikes
// ---------------------------------------------------------------------------
__global__ __launch_bounds__(256) void k4_lif2(
    const float* __restrict__ oatt,
    const float* __restrict__ p0, const float* __restrict__ p1,
    const float* __restrict__ p2, const float* __restrict__ p3,
    uint32_t* __restrict__ s2c)
{
    const int c = threadIdx.x;
    const int n = blockIdx.x;
    const int b = blockIdx.y;
    const int lane = c & 63;
    float memv = 0.0f, spk = 0.0f;
    for (int t = 0; t < T_; ++t) {
        const int l = t * N_ + n;
        float v = oatt[((size_t)b * TN_ + l) * C_ + c];
        v += p0[((size_t)b * 1024 + l) * 256 + c];
        if (t >= 1) v += p1[((size_t)b * 768 + (l - 256)) * 256 + c];
        if (t >= 2) v += p2[((size_t)b * 512 + (l - 512)) * 256 + c];
        if (t >= 3) v += p3[((size_t)b * 256 + (l - 768)) * 256 + c];
        const float m = (memv - 0.5f * spk) * 0.25f + 0.125f * v;
        memv = m;
        const float s = quant1f(m);
        spk = s;
        const uint64_t mask = __ballot(s != 0.0f);
        if (lane == 0)
            s2c[((size_t)b * TN_ + l) * 8 + (c >> 5)] = (uint32_t)mask;
        else if (lane == 32)
            s2c[((size_t)b * TN_ + l) * 8 + (c >> 5)] = (uint32_t)(mask >> 32);
    }
}

// ---------------------------------------------------------------------------
// K5: fused proj GEMM + bias + BN + final LIF -> writes d_out directly.
// Tile 32 o-rows x [4t x 32n] cols; each thread owns all 4 t for its (row,n)
// so the LIF chain lives in registers. w-tile staged per K-half (no barriers
// inside the k-loop); B bits held in registers. Grid 8x8x8 = 512 blocks.
// Ascending-k accumulation == prior rounds (bit-identical pre-LIF values).
// ---------------------------------------------------------------------------
__global__ __launch_bounds__(256) void k5_proj_lif(
    const uint32_t* __restrict__ s2c, const float* __restrict__ w,
    const float* __restrict__ bp,
    const float* __restrict__ gamma, const float* __restrict__ beta,
    const float* __restrict__ mean, const float* __restrict__ var,
    float* __restrict__ out)
{
    __shared__ float At[128][36];    // [k-local][row], 32 rows (+4 pad)
    __shared__ uint32_t Sw[128 * 9]; // [l'][8 words] padded to 9
    const int nBase = blockIdx.x * 32;
    const int oBase = blockIdx.y * 32;
    const int b = blockIdx.z;
    const int tid = threadIdx.x;
    const int tx = tid & 31;   // n = nBase + tx
    const int ty = tid >> 5;   // rows ty*4..+3

    // stage spike words for this block's 128 l's (4t x 32n), once
#pragma unroll
    for (int j = 0; j < 4; ++j) {
        const int fidx = tid * 4 + j;          // 0..1023
        const int lp = fidx >> 3, wsel = fidx & 7;
        const int t = lp >> 5, nn = lp & 31;
        Sw[lp * 9 + wsel] = s2c[((size_t)b * TN_ + t * 256 + nBase + nn) * 8 + wsel];
    }

    const int a_row = tid >> 3, a_kq = (tid & 7) * 16;

    float acc[4][4];
#pragma unroll
    for (int r = 0; r < 4; ++r)
#pragma unroll
        for (int t = 0; t < 4; ++t) acc[r][t] = 0.0f;

    for (int half = 0; half < 2; ++half) {
        if (half) __syncthreads();   // previous half's reads done
        // stage At: 32 rows x 128 k (this half), transposed scalar stores
#pragma unroll
        for (int j = 0; j < 4; ++j) {
            const float4 v = *(const float4*)&w[(size_t)(oBase + a_row) * C_ + half * 128 + a_kq + 4 * j];
            At[a_kq + 4 * j][a_row] = v.x;
            At[a_kq + 4 * j + 1][a_row] = v.y;
            At[a_kq + 4 * j + 2][a_row] = v.z;
            At[a_kq + 4 * j + 3][a_row] = v.w;
        }
        __syncthreads();

        for (int ks = 0; ks < 4; ++ks) {
            uint32_t wr[4];
#pragma unroll
            for (int t = 0; t < 4; ++t)
                wr[t] = Sw[(t * 32 + tx) * 9 + half * 4 + ks];
#pragma unroll
            for (int u = 0; u < 32; ++u) {
                float a[4];
                *(float4*)&a[0] = *(const float4*)&At[ks * 32 + u][ty * 4];
                float bv[4];
#pragma unroll
                for (int t = 0; t < 4; ++t) bv[t] = (float)((wr[t] >> u) & 1u);
#pragma unroll
                for (int r = 0; r < 4; ++r)
#pragma unroll
                    for (int t = 0; t < 4; ++t) acc[r][t] += a[r] * bv[t];
            }
        }
    }

    // epilogue: bias + BN + LIF over t, write final output
#pragma unroll
    for (int r = 0; r < 4; ++r) {
        const int o = oBase + ty * 4 + r;
        const float inv = 1.0f / sqrtf(var[o] + 1e-5f);
        const float g = gamma[o] * inv;
        const float mn = mean[o], bt = beta[o], bpo = bp[o];
        float memv = 0.0f, spk = 0.0f;
#pragma unroll
        for (int t = 0; t < 4; ++t) {
            const float val = ((acc[r][t] + bpo) - mn) * g + bt;
            const float m = (memv - 0.5f * spk) * 0.25f + val;
            memv = m;
            const float s = quant1f(m);
            spk = s;
            out[(((size_t)t * B_ + b) * C_ + o) * N_ + nBase + tx] = s;
        }
    }
}

// ---------------------------------------------------------------------------
extern "C" void kernel_launch(void* const* d_in, const int* in_sizes, int n_in,
                              void* d_out, int out_size, void* d_ws, size_t ws_size,
                              hipStream_t stream)
{
    const float* x          = (const float*)d_in[0];
    const float* w_qkv      = (const float*)d_in[1];
    const float* qkv_gamma  = (const float*)d_in[2];
    const float* qkv_beta   = (const float*)d_in[3];
    const float* qkv_mean   = (const float*)d_in[4];
    const float* qkv_var    = (const float*)d_in[5];
    const float* bias_table = (const float*)d_in[6];
    const float* w_proj     = (const float*)d_in[7];
    const float* b_proj     = (const float*)d_in[8];
    const float* proj_gamma = (const float*)d_in[9];
    const float* proj_beta  = (const float*)d_in[10];
    const float* proj_mean  = (const float*)d_in[11];
    const float* proj_var   = (const float*)d_in[12];
    float* out = (float*)d_out;

    // workspace layout (bytes)
    char* ws = (char*)d_ws;
    float*    qkv_bn = (float*)(ws + 0);            // 25165824 B (dead after K2)
    float*    Gf     = (float*)(ws + 524288);       //   262144 B (after K2)
    float*    part0  = (float*)(ws + 1048576);      //  8388608 B
    float*    part1  = (float*)(ws + 9437184);      //  6291456 B
    float*    part2  = (float*)(ws + 15728640);     //  4194304 B
    float*    part3  = (float*)(ws + 19922944);     //  2097152 B
    float*    oatt   = (float*)(ws + 25165824);     //  8388608 B (S1, unscaled)
    uint32_t* s2c    = (uint32_t*)(ws + 33554432);  //   262144 B (packed spikes)
    uint32_t* qbits  = (uint32_t*)(ws + 50331648);  //   262144 B
    uint32_t* kbits  = (uint32_t*)(ws + 50593792);
    uint32_t* vbits  = (uint32_t*)(ws + 50855936);  // end 51118080

    k1_qkv_gemm<<<dim3(4, 8, 8), 256, 0, stream>>>(
        x, w_qkv, qkv_gamma, qkv_beta, qkv_mean, qkv_var, qkv_bn);

    k2_lif_pack<<<dim3(24, 8, 2), 256, 0, stream>>>(qkv_bn, qbits, kbits, vbits);

    k3_tg<<<dim3(64), 256, 0, stream>>>(kbits, vbits, Gf);

    k3_s1<<<dim3(16, 8, 8), 256, 0, stream>>>(qbits, Gf, oatt);

    k3_bias_gemm<<<dim3(2, 4, 80), 256, 0, stream>>>(
        vbits, bias_table, part0, part1, part2, part3);

    k4_lif2<<<dim3(256, 8), 256, 0, stream>>>(oatt, part0, part1, part2, part3, s2c);

    k5_proj_lif<<<dim3(8, 8, 8), 256, 0, stream>>>(
        s2c, w_proj, b_proj, proj_gamma, proj_beta, proj_mean, proj_var, out);
}

// Round 9
// 231.596 us; speedup vs baseline: 1.0832x; 1.0832x over previous
//
#include <hip/hip_runtime.h>
#include <stdint.h>
#include <math.h>

// Problem constants
constexpr int T_ = 4;
constexpr int B_ = 8;
constexpr int C_ = 256;
constexpr int N_ = 256;          // H*W
constexpr int TN_ = 1024;        // T*N
constexpr int NH_ = 8;           // heads
constexpr int O3_ = 768;         // 3*C
constexpr int BIAS_ROWS_ = 6727; // 7*31*31

__device__ __constant__ int TI_OF[10] = {0,1,1,2,2,2,3,3,3,3};
__device__ __constant__ int TJ_OF[10] = {0,0,1,0,1,2,0,1,2,3};

__device__ __forceinline__ float quant1f(float m) {
    return rintf(fminf(fmaxf(m, 0.0f), 1.0f));
}

// ---------------------------------------------------------------------------
// K1: qkv = BN(w_qkv @ xf)   out[b][o][l]
// 64(M) x 128(N) tile, 256 threads, 8x4 microtile, K-chunk 16.  (R6 config:
// 57 us measured; 96x256 (R7) regressed via 4-8-way LDS conflicts.)
// Grid 8x12x8 = 768 blocks = 3/CU. Ascending-k accumulation (bit-identical).
// ---------------------------------------------------------------------------
__global__ __launch_bounds__(256) void k1_qkv_gemm(
    const float* __restrict__ x, const float* __restrict__ w,
    const float* __restrict__ gamma, const float* __restrict__ beta,
    const float* __restrict__ mean, const float* __restrict__ var,
    float* __restrict__ out)
{
    __shared__ float At[16][68];   // [k][m], m=64 (+4 pad)
    __shared__ float Bt[16][132];  // [k][n], n=128 (+4 pad)
    const int b = blockIdx.z;
    const int oBase = blockIdx.y * 64;
    const int lBase = blockIdx.x * 128;
    const int tid = threadIdx.x;
    const int tx = tid & 31;        // n: cols tx*4..+3
    const int ty = tid >> 5;        // m: rows {0,32}+ty*4..+3
    const float* xb = x + (size_t)b * C_ * TN_;

    float acc[8][4];
#pragma unroll
    for (int i = 0; i < 8; ++i)
#pragma unroll
        for (int j = 0; j < 4; ++j) acc[i][j] = 0.0f;

    const int b_kk = tid >> 4, b_c4 = (tid & 15) * 4;
    const int a_row = tid >> 3, a_k2 = (tid & 7) * 2;

    for (int kc = 0; kc < 16; ++kc) {
        const int k0 = kc * 16;
#pragma unroll
        for (int r = 0; r < 2; ++r) {
            const int row = a_row + 32 * r;
            const float2 v = *(const float2*)&w[(size_t)(oBase + row) * C_ + k0 + a_k2];
            At[a_k2][row] = v.x;
            At[a_k2 + 1][row] = v.y;
        }
#pragma unroll
        for (int r = 0; r < 2; ++r) {
            const float4 v = *(const float4*)&xb[(size_t)(k0 + b_kk) * TN_ + lBase + b_c4 + 64 * r];
            *(float4*)&Bt[b_kk][b_c4 + 64 * r] = v;
        }
        __syncthreads();
#pragma unroll
        for (int cc = 0; cc < 16; ++cc) {
            float a[8], bb[4];
            *(float4*)&a[0] = *(const float4*)&At[cc][ty * 4];
            *(float4*)&a[4] = *(const float4*)&At[cc][32 + ty * 4];
            *(float4*)&bb[0] = *(const float4*)&Bt[cc][tx * 4];
#pragma unroll
            for (int i = 0; i < 8; ++i)
#pragma unroll
                for (int j = 0; j < 4; ++j) acc[i][j] += a[i] * bb[j];
        }
        __syncthreads();
    }

#pragma unroll
    for (int i = 0; i < 8; ++i) {
        const int o = oBase + (i >> 2) * 32 + ty * 4 + (i & 3);
        const float inv = 1.0f / sqrtf(var[o] + 1e-5f);
        const float g = gamma[o] * inv;
        const float mn = mean[o], bt = beta[o];
        float4 st;
        st.x = (acc[i][0] - mn) * g + bt;
        st.y = (acc[i][1] - mn) * g + bt;
        st.z = (acc[i][2] - mn) * g + bt;
        st.w = (acc[i][3] - mn) * g + bt;
        *(float4*)&out[((size_t)b * O3_ + o) * TN_ + lBase + tx * 4] = st;
    }
}

// ---------------------------------------------------------------------------
// K2: LIF over t on qkv_bn, pack 32 head-dims into one uint32 spike word.
// ---------------------------------------------------------------------------
__global__ __launch_bounds__(256) void k2_lif_pack(
    const float* __restrict__ qkv,
    uint32_t* __restrict__ qb, uint32_t* __restrict__ kb, uint32_t* __restrict__ vb)
{
    const int n = threadIdx.x;
    const int g = blockIdx.x;
    const int b = blockIdx.y;
    const int which = g >> 3, h = g & 7;
    uint32_t* dst = (which == 0) ? qb : (which == 1) ? kb : vb;
    const float* src = qkv + ((size_t)b * O3_ + g * 32) * TN_;

    float memv[32];
#pragma unroll
    for (int d = 0; d < 32; ++d) memv[d] = 0.0f;
    uint32_t prev = 0;

    for (int t = 0; t < T_; ++t) {
        uint32_t bits = 0;
#pragma unroll
        for (int d = 0; d < 32; ++d) {
            const float xv = src[(size_t)d * TN_ + t * N_ + n];
            const float m = (memv[d] - 0.5f * (float)((prev >> d) & 1u)) * 0.25f + xv;
            memv[d] = m;
            const float s = quant1f(m);
            bits |= ((uint32_t)s) << d;
        }
        prev = bits;
        dst[((size_t)b * NH_ + h) * TN_ + t * N_ + n] = bits;
    }
}

// ---------------------------------------------------------------------------
// K3tg: fused ballot bit-transpose + cumulative Gram matrix, one block per bh.
// ---------------------------------------------------------------------------
__global__ __launch_bounds__(256) void k3_tg(
    const uint32_t* __restrict__ kb, const uint32_t* __restrict__ vb,
    float* __restrict__ Gf)
{
    __shared__ uint64_t ks[4][32][4];
    __shared__ uint64_t vs[4][32][4];
    const int bh = blockIdx.x;
    const int tid = threadIdx.x;
    const int q = tid >> 6, lane = tid & 63;

#pragma unroll
    for (int t = 0; t < T_; ++t) {
        const int j = t * N_ + q * 64 + lane;
        const uint32_t kw = kb[(size_t)bh * TN_ + j];
        const uint32_t vw = vb[(size_t)bh * TN_ + j];
#pragma unroll
        for (int d = 0; d < 32; ++d) {
            const uint64_t mk = __ballot((kw >> d) & 1u);
            const uint64_t mv = __ballot((vw >> d) & 1u);
            if (lane == 0) { ks[t][d][q] = mk; vs[t][d][q] = mv; }
        }
    }
    __syncthreads();

    const int d = tid & 31;
#pragma unroll
    for (int s = 0; s < 4; ++s) {
        const int d2 = (tid >> 5) + 8 * s;
        int cum = 0;
#pragma unroll
        for (int t = 0; t < T_; ++t) {
            int p = 0;
#pragma unroll
            for (int w = 0; w < 4; ++w) p += __popcll(ks[t][d2][w] & vs[t][d][w]);
            cum += p;
            Gf[(size_t)(bh * 4 + t) * 1024 + d2 * 32 + d] = (float)cum;
        }
    }
}

// ---------------------------------------------------------------------------
// K3gemm: balanced split-K bias GEMM (R6 config).
// ---------------------------------------------------------------------------
__global__ __launch_bounds__(256) void k3_bias_gemm(
    const uint32_t* __restrict__ vb, const float* __restrict__ bias_table,
    float* __restrict__ p0, float* __restrict__ p1,
    float* __restrict__ p2, float* __restrict__ p3)
{
    __shared__ float sbl[640];
    __shared__ float At[16][68];
    __shared__ float Bt[16][132];

    const int z = blockIdx.z;
    const int h = z / 10;
    const int p = z % 10;
    const int ti = TI_OF[p], tj = TJ_OF[p];
    const int dt = ti - tj;
    const int iT = blockIdx.y;
    const int nBase = blockIdx.x * 128;
    const int tid = threadIdx.x;

    const int base = 3363 + 961 * dt + 124 * iT - 480;
    for (int s = tid; s < 640; s += 256) {
        const int gidx = base + s;
        sbl[s] = (gidx < BIAS_ROWS_) ? bias_table[(size_t)gidx * NH_ + h] : 0.0f;
    }

    const int ty = tid >> 4, tx = tid & 15;

    const int ccS = tx;
    const int iBase4 = ty * 4;
    const int sIdxBase = 31 * (iBase4 >> 4) + (iBase4 & 15) + 480 - ccS;

    const int kkS = ty;
    const int n8 = tx * 8;
    const int nS = nBase + n8;
    const int bS = nS >> 5, d0S = nS & 31;
    const uint32_t* vbw = vb + ((size_t)bS * NH_ + h) * TN_ + tj * 256 + kkS;

    float acc[4][8];
#pragma unroll
    for (int i = 0; i < 4; ++i)
#pragma unroll
        for (int j = 0; j < 8; ++j) acc[i][j] = 0.0f;

    __syncthreads();

    for (int kc = 0; kc < 16; ++kc) {
        {
            const int s0 = sIdxBase - 31 * kc;
            float4 av;
            av.x = sbl[s0];
            av.y = sbl[s0 + 1];
            av.z = sbl[s0 + 2];
            av.w = sbl[s0 + 3];
            *(float4*)&At[ccS][iBase4] = av;
        }
        {
            const uint32_t wd = vbw[kc * 16];
            float4 b0, b1;
            b0.x = (float)((wd >> d0S) & 1u);
            b0.y = (float)((wd >> (d0S + 1)) & 1u);
            b0.z = (float)((wd >> (d0S + 2)) & 1u);
            b0.w = (float)((wd >> (d0S + 3)) & 1u);
            b1.x = (float)((wd >> (d0S + 4)) & 1u);
            b1.y = (float)((wd >> (d0S + 5)) & 1u);
            b1.z = (float)((wd >> (d0S + 6)) & 1u);
            b1.w = (float)((wd >> (d0S + 7)) & 1u);
            *(float4*)&Bt[kkS][n8] = b0;
            *(float4*)&Bt[kkS][n8 + 4] = b1;
        }
        __syncthreads();
#pragma unroll
        for (int cc = 0; cc < 16; ++cc) {
            float a[4], bb[8];
            *(float4*)&a[0] = *(const float4*)&At[cc][ty * 4];
            *(float4*)&bb[0] = *(const float4*)&Bt[cc][tx * 8];
            *(float4*)&bb[4] = *(const float4*)&Bt[cc][tx * 8 + 4];
#pragma unroll
            for (int i = 0; i < 4; ++i)
#pragma unroll
                for (int j = 0; j < 8; ++j) acc[i][j] += a[i] * bb[j];
        }
        __syncthreads();
    }

    float* plane = (tj == 0) ? p0 : (tj == 1) ? p1 : (tj == 2) ? p2 : p3;
    const int nrows = (4 - tj) * 256;
    const int c0 = h * 32 + d0S;
#pragma unroll
    for (int r = 0; r < 4; ++r) {
        const int rowL = dt * 256 + iT * 64 + ty * 4 + r;
        float* dst = &plane[((size_t)bS * nrows + rowL) * 256 + c0];
        float4 s0, s1;
        s0.x = acc[r][0]; s0.y = acc[r][1]; s0.z = acc[r][2]; s0.w = acc[r][3];
        s1.x = acc[r][4]; s1.y = acc[r][5]; s1.z = acc[r][6]; s1.w = acc[r][7];
        *(float4*)&dst[0] = s0;
        *(float4*)&dst[4] = s1;
    }
}

// ---------------------------------------------------------------------------
// K4: fused S1 + bias partials + LIF2 -> bit-packed spikes.
// S1 computed inline per (b,n,c): q-word broadcast + 32 L2-hot Gf loads,
// ascending-d2 add order == old k3_s1 (bit-identical).
// ---------------------------------------------------------------------------
__global__ __launch_bounds__(256) void k4_lif2(
    const uint32_t* __restrict__ qb, const float* __restrict__ Gf,
    const float* __restrict__ p0, const float* __restrict__ p1,
    const float* __restrict__ p2, const float* __restrict__ p3,
    uint32_t* __restrict__ s2c)
{
    const int c = threadIdx.x;
    const int n = blockIdx.x;
    const int b = blockIdx.y;
    const int lane = c & 63;
    const int h = c >> 5, d = c & 31;
    const int bh = b * NH_ + h;
    const uint32_t* qbh = qb + (size_t)bh * TN_;

    float memv = 0.0f, spk = 0.0f;
    for (int t = 0; t < T_; ++t) {
        const int l = t * N_ + n;
        // S1 inline
        const uint32_t q = qbh[l];
        const float* g = Gf + (size_t)(bh * 4 + t) * 1024 + d;
        float v = 0.0f;
#pragma unroll
        for (int d2 = 0; d2 < 32; ++d2)
            v += ((q >> d2) & 1u) ? g[d2 * 32] : 0.0f;
        // bias partials (deterministic fixed order)
        v += p0[((size_t)b * 1024 + l) * 256 + c];
        if (t >= 1) v += p1[((size_t)b * 768 + (l - 256)) * 256 + c];
        if (t >= 2) v += p2[((size_t)b * 512 + (l - 512)) * 256 + c];
        if (t >= 3) v += p3[((size_t)b * 256 + (l - 768)) * 256 + c];
        const float m = (memv - 0.5f * spk) * 0.25f + 0.125f * v;
        memv = m;
        const float s = quant1f(m);
        spk = s;
        const uint64_t mask = __ballot(s != 0.0f);
        if (lane == 0)
            s2c[((size_t)b * TN_ + l) * 8 + (c >> 5)] = (uint32_t)mask;
        else if (lane == 32)
            s2c[((size_t)b * TN_ + l) * 8 + (c >> 5)] = (uint32_t)(mask >> 32);
    }
}

// ---------------------------------------------------------------------------
// K5: fused proj GEMM + bias + BN + final LIF -> writes d_out directly.
// ---------------------------------------------------------------------------
__global__ __launch_bounds__(256) void k5_proj_lif(
    const uint32_t* __restrict__ s2c, const float* __restrict__ w,
    const float* __restrict__ bp,
    const float* __restrict__ gamma, const float* __restrict__ beta,
    const float* __restrict__ mean, const float* __restrict__ var,
    float* __restrict__ out)
{
    __shared__ float At[128][36];    // [k-local][row], 32 rows (+4 pad)
    __shared__ uint32_t Sw[128 * 9]; // [l'][8 words] padded to 9
    const int nBase = blockIdx.x * 32;
    const int oBase = blockIdx.y * 32;
    const int b = blockIdx.z;
    const int tid = threadIdx.x;
    const int tx = tid & 31;   // n = nBase + tx
    const int ty = tid >> 5;   // rows ty*4..+3

#pragma unroll
    for (int j = 0; j < 4; ++j) {
        const int fidx = tid * 4 + j;
        const int lp = fidx >> 3, wsel = fidx & 7;
        const int t = lp >> 5, nn = lp & 31;
        Sw[lp * 9 + wsel] = s2c[((size_t)b * TN_ + t * 256 + nBase + nn) * 8 + wsel];
    }

    const int a_row = tid >> 3, a_kq = (tid & 7) * 16;

    float acc[4][4];
#pragma unroll
    for (int r = 0; r < 4; ++r)
#pragma unroll
        for (int t = 0; t < 4; ++t) acc[r][t] = 0.0f;

    for (int half = 0; half < 2; ++half) {
        if (half) __syncthreads();
#pragma unroll
        for (int j = 0; j < 4; ++j) {
            const float4 v = *(const float4*)&w[(size_t)(oBase + a_row) * C_ + half * 128 + a_kq + 4 * j];
            At[a_kq + 4 * j][a_row] = v.x;
            At[a_kq + 4 * j + 1][a_row] = v.y;
            At[a_kq + 4 * j + 2][a_row] = v.z;
            At[a_kq + 4 * j + 3][a_row] = v.w;
        }
        __syncthreads();

        for (int ks = 0; ks < 4; ++ks) {
            uint32_t wr[4];
#pragma unroll
            for (int t = 0; t < 4; ++t)
                wr[t] = Sw[(t * 32 + tx) * 9 + half * 4 + ks];
#pragma unroll
            for (int u = 0; u < 32; ++u) {
                float a[4];
                *(float4*)&a[0] = *(const float4*)&At[ks * 32 + u][ty * 4];
                float bv[4];
#pragma unroll
                for (int t = 0; t < 4; ++t) bv[t] = (float)((wr[t] >> u) & 1u);
#pragma unroll
                for (int r = 0; r < 4; ++r)
#pragma unroll
                    for (int t = 0; t < 4; ++t) acc[r][t] += a[r] * bv[t];
            }
        }
    }

#pragma unroll
    for (int r = 0; r < 4; ++r) {
        const int o = oBase + ty * 4 + r;
        const float inv = 1.0f / sqrtf(var[o] + 1e-5f);
        const float g = gamma[o] * inv;
        const float mn = mean[o], bt = beta[o], bpo = bp[o];
        float memv = 0.0f, spk = 0.0f;
#pragma unroll
        for (int t = 0; t < 4; ++t) {
            const float val = ((acc[r][t] + bpo) - mn) * g + bt;
            const float m = (memv - 0.5f * spk) * 0.25f + val;
            memv = m;
            const float s = quant1f(m);
            spk = s;
            out[(((size_t)t * B_ + b) * C_ + o) * N_ + nBase + tx] = s;
        }
    }
}

// ---------------------------------------------------------------------------
extern "C" void kernel_launch(void* const* d_in, const int* in_sizes, int n_in,
                              void* d_out, int out_size, void* d_ws, size_t ws_size,
                              hipStream_t stream)
{
    const float* x          = (const float*)d_in[0];
    const float* w_qkv      = (const float*)d_in[1];
    const float* qkv_gamma  = (const float*)d_in[2];
    const float* qkv_beta   = (const float*)d_in[3];
    const float* qkv_mean   = (const float*)d_in[4];
    const float* qkv_var    = (const float*)d_in[5];
    const float* bias_table = (const float*)d_in[6];
    const float* w_proj     = (const float*)d_in[7];
    const float* b_proj     = (const float*)d_in[8];
    const float* proj_gamma = (const float*)d_in[9];
    const float* proj_beta  = (const float*)d_in[10];
    const float* proj_mean  = (const float*)d_in[11];
    const float* proj_var   = (const float*)d_in[12];
    float* out = (float*)d_out;

    // workspace layout (bytes).  NOTE: Gf is 1 MiB (64 bh x 4 t x 1024 f32)
    // and in R8 it overlapped part0 -> corrupted reads in fused k4 (the R8
    // failure). It now lives in the dead oatt region, overlap-free.
    char* ws = (char*)d_ws;
    float*    qkv_bn = (float*)(ws + 0);            // 25165824 B (dead after K2)
    float*    part0  = (float*)(ws + 1048576);      //  8388608 B (after K2)
    float*    part1  = (float*)(ws + 9437184);      //  6291456 B
    float*    part2  = (float*)(ws + 15728640);     //  4194304 B
    float*    part3  = (float*)(ws + 19922944);     //  2097152 B (end 22020096)
    float*    Gf     = (float*)(ws + 25165824);     //  1048576 B (end 26214400)
    uint32_t* s2c    = (uint32_t*)(ws + 33554432);  //   262144 B (packed spikes)
    uint32_t* qbits  = (uint32_t*)(ws + 50331648);  //   262144 B
    uint32_t* kbits  = (uint32_t*)(ws + 50593792);
    uint32_t* vbits  = (uint32_t*)(ws + 50855936);  // end 51118080

    k1_qkv_gemm<<<dim3(8, 12, 8), 256, 0, stream>>>(
        x, w_qkv, qkv_gamma, qkv_beta, qkv_mean, qkv_var, qkv_bn);

    k2_lif_pack<<<dim3(24, 8), 256, 0, stream>>>(qkv_bn, qbits, kbits, vbits);

    k3_tg<<<dim3(64), 256, 0, stream>>>(kbits, vbits, Gf);

    k3_bias_gemm<<<dim3(2, 4, 80), 256, 0, stream>>>(
        vbits, bias_table, part0, part1, part2, part3);

    k4_lif2<<<dim3(256, 8), 256, 0, stream>>>(
        qbits, Gf, part0, part1, part2, part3, s2c);

    k5_proj_lif<<<dim3(8, 8, 8), 256, 0, stream>>>(
        s2c, w_proj, b_proj, proj_gamma, proj_beta, proj_mean, proj_var, out);
}

// Round 10
// 226.547 us; speedup vs baseline: 1.1073x; 1.0223x over previous
//
#include <hip/hip_runtime.h>
#include <stdint.h>
#include <math.h>

// Problem constants
constexpr int T_ = 4;
constexpr int B_ = 8;
constexpr int C_ = 256;
constexpr int N_ = 256;          // H*W
constexpr int TN_ = 1024;        // T*N
constexpr int NH_ = 8;           // heads
constexpr int O3_ = 768;         // 3*C
constexpr int BIAS_ROWS_ = 6727; // 7*31*31

__device__ __constant__ int TI_OF[10] = {0,1,1,2,2,2,3,3,3,3};
__device__ __constant__ int TJ_OF[10] = {0,0,1,0,1,2,0,1,2,3};

__device__ __forceinline__ float quant1f(float m) {
    return rintf(fminf(fmaxf(m, 0.0f), 1.0f));
}

// ---------------------------------------------------------------------------
// K1: qkv = BN(w_qkv @ xf)   out[b][o][l]
// 64(M) x 128(N) tile, 256 threads, 8x4 microtile, K-chunk 32 (16 barriers
// per block vs R6's 32 -- R9 showed k1 is VALU-issue-bound at 43% with
// grid-limited 3 blocks/CU; fewer barrier events is the remaining lever).
// Ascending-k accumulation (bit-identical to prior rounds).
// ---------------------------------------------------------------------------
__global__ __launch_bounds__(256) void k1_qkv_gemm(
    const float* __restrict__ x, const float* __restrict__ w,
    const float* __restrict__ gamma, const float* __restrict__ beta,
    const float* __restrict__ mean, const float* __restrict__ var,
    float* __restrict__ out)
{
    __shared__ float At[32][68];   // [k][m], m=64 (+4 pad)
    __shared__ float Bt[32][132];  // [k][n], n=128 (+4 pad)
    const int b = blockIdx.z;
    const int oBase = blockIdx.y * 64;
    const int lBase = blockIdx.x * 128;
    const int tid = threadIdx.x;
    const int tx = tid & 31;        // n: cols tx*4..+3
    const int ty = tid >> 5;        // m: rows {0,32}+ty*4..+3
    const float* xb = x + (size_t)b * C_ * TN_;

    float acc[8][4];
#pragma unroll
    for (int i = 0; i < 8; ++i)
#pragma unroll
        for (int j = 0; j < 4; ++j) acc[i][j] = 0.0f;

    // A loader: 64 rows x 32 k = 1024 float2; row=(tid>>4)+16r, k2=(tid&15)*2
    const int a_row0 = tid >> 4, a_k2 = (tid & 15) * 2;
    // B loader: 32 k x 128 l = 1024 float4; kk=(tid>>5)+8r, c4=(tid&31)*4
    const int b_kk0 = tid >> 5, b_c4 = (tid & 31) * 4;

    for (int kc = 0; kc < 8; ++kc) {
        const int k0 = kc * 32;
#pragma unroll
        for (int r = 0; r < 4; ++r) {
            const int row = a_row0 + 16 * r;
            const float2 v = *(const float2*)&w[(size_t)(oBase + row) * C_ + k0 + a_k2];
            At[a_k2][row] = v.x;
            At[a_k2 + 1][row] = v.y;
        }
#pragma unroll
        for (int r = 0; r < 4; ++r) {
            const int kk = b_kk0 + 8 * r;
            const float4 v = *(const float4*)&xb[(size_t)(k0 + kk) * TN_ + lBase + b_c4];
            *(float4*)&Bt[kk][b_c4] = v;
        }
        __syncthreads();
#pragma unroll
        for (int cc = 0; cc < 32; ++cc) {
            float a[8], bb[4];
            *(float4*)&a[0] = *(const float4*)&At[cc][ty * 4];
            *(float4*)&a[4] = *(const float4*)&At[cc][32 + ty * 4];
            *(float4*)&bb[0] = *(const float4*)&Bt[cc][tx * 4];
#pragma unroll
            for (int i = 0; i < 8; ++i)
#pragma unroll
                for (int j = 0; j < 4; ++j) acc[i][j] += a[i] * bb[j];
        }
        __syncthreads();
    }

#pragma unroll
    for (int i = 0; i < 8; ++i) {
        const int o = oBase + (i >> 2) * 32 + ty * 4 + (i & 3);
        const float inv = 1.0f / sqrtf(var[o] + 1e-5f);
        const float g = gamma[o] * inv;
        const float mn = mean[o], bt = beta[o];
        float4 st;
        st.x = (acc[i][0] - mn) * g + bt;
        st.y = (acc[i][1] - mn) * g + bt;
        st.z = (acc[i][2] - mn) * g + bt;
        st.w = (acc[i][3] - mn) * g + bt;
        *(float4*)&out[((size_t)b * O3_ + o) * TN_ + lBase + tx * 4] = st;
    }
}

// ---------------------------------------------------------------------------
// K2: LIF over t on qkv_bn, pack 32 head-dims into one uint32 spike word.
// ---------------------------------------------------------------------------
__global__ __launch_bounds__(256) void k2_lif_pack(
    const float* __restrict__ qkv,
    uint32_t* __restrict__ qb, uint32_t* __restrict__ kb, uint32_t* __restrict__ vb)
{
    const int n = threadIdx.x;
    const int g = blockIdx.x;
    const int b = blockIdx.y;
    const int which = g >> 3, h = g & 7;
    uint32_t* dst = (which == 0) ? qb : (which == 1) ? kb : vb;
    const float* src = qkv + ((size_t)b * O3_ + g * 32) * TN_;

    float memv[32];
#pragma unroll
    for (int d = 0; d < 32; ++d) memv[d] = 0.0f;
    uint32_t prev = 0;

    for (int t = 0; t < T_; ++t) {
        uint32_t bits = 0;
#pragma unroll
        for (int d = 0; d < 32; ++d) {
            const float xv = src[(size_t)d * TN_ + t * N_ + n];
            const float m = (memv[d] - 0.5f * (float)((prev >> d) & 1u)) * 0.25f + xv;
            memv[d] = m;
            const float s = quant1f(m);
            bits |= ((uint32_t)s) << d;
        }
        prev = bits;
        dst[((size_t)b * NH_ + h) * TN_ + t * N_ + n] = bits;
    }
}

// ---------------------------------------------------------------------------
// K3tg: fused ballot bit-transpose + cumulative Gram matrix, one block per bh.
// ---------------------------------------------------------------------------
__global__ __launch_bounds__(256) void k3_tg(
    const uint32_t* __restrict__ kb, const uint32_t* __restrict__ vb,
    float* __restrict__ Gf)
{
    __shared__ uint64_t ks[4][32][4];
    __shared__ uint64_t vs[4][32][4];
    const int bh = blockIdx.x;
    const int tid = threadIdx.x;
    const int q = tid >> 6, lane = tid & 63;

#pragma unroll
    for (int t = 0; t < T_; ++t) {
        const int j = t * N_ + q * 64 + lane;
        const uint32_t kw = kb[(size_t)bh * TN_ + j];
        const uint32_t vw = vb[(size_t)bh * TN_ + j];
#pragma unroll
        for (int d = 0; d < 32; ++d) {
            const uint64_t mk = __ballot((kw >> d) & 1u);
            const uint64_t mv = __ballot((vw >> d) & 1u);
            if (lane == 0) { ks[t][d][q] = mk; vs[t][d][q] = mv; }
        }
    }
    __syncthreads();

    const int d = tid & 31;
#pragma unroll
    for (int s = 0; s < 4; ++s) {
        const int d2 = (tid >> 5) + 8 * s;
        int cum = 0;
#pragma unroll
        for (int t = 0; t < T_; ++t) {
            int p = 0;
#pragma unroll
            for (int w = 0; w < 4; ++w) p += __popcll(ks[t][d2][w] & vs[t][d][w]);
            cum += p;
            Gf[(size_t)(bh * 4 + t) * 1024 + d2 * 32 + d] = (float)cum;
        }
    }
}

// ---------------------------------------------------------------------------
// K3gemm: balanced split-K bias GEMM, K-chunk 32 (halved barrier count).
// Block = (nT 128 cols, iT 64 rows, h*10+pair); K = 256 (one tj), 640 blocks.
// j ascending inner order == prior rounds (bit-identical).
// ---------------------------------------------------------------------------
__global__ __launch_bounds__(256) void k3_bias_gemm(
    const uint32_t* __restrict__ vb, const float* __restrict__ bias_table,
    float* __restrict__ p0, float* __restrict__ p1,
    float* __restrict__ p2, float* __restrict__ p3)
{
    __shared__ float sbl[640];
    __shared__ float At[32][68];   // [j-in-chunk][i-local]
    __shared__ float Bt[32][132];  // [j-in-chunk][n-local]

    const int z = blockIdx.z;
    const int h = z / 10;
    const int p = z % 10;
    const int ti = TI_OF[p], tj = TJ_OF[p];
    const int dt = ti - tj;
    const int iT = blockIdx.y;
    const int nBase = blockIdx.x * 128;
    const int tid = threadIdx.x;

    const int base = 3363 + 961 * dt + 124 * iT - 480;
    for (int s = tid; s < 640; s += 256) {
        const int gidx = base + s;
        sbl[s] = (gidx < BIAS_ROWS_) ? bias_table[(size_t)gidx * NH_ + h] : 0.0f;
    }

    const int ty = tid >> 4, tx = tid & 15;

    // A-staging: cc = tx + 16r (r=0,1), rows iBase4..+3; hj = kc*2 + r, wj = tx
    const int iBase4 = ty * 4;
    const int sIdxBase = 31 * (iBase4 >> 4) + (iBase4 & 15) + 480 - tx;

    // B-staging: rows kk = ty + 16r
    const int n8 = tx * 8;
    const int nS = nBase + n8;
    const int bS = nS >> 5, d0S = nS & 31;
    const uint32_t* vbw = vb + ((size_t)bS * NH_ + h) * TN_ + tj * 256 + ty;

    float acc[4][8];
#pragma unroll
    for (int i = 0; i < 4; ++i)
#pragma unroll
        for (int j = 0; j < 8; ++j) acc[i][j] = 0.0f;

    __syncthreads();  // sbl ready

    for (int kc = 0; kc < 8; ++kc) {
#pragma unroll
        for (int r = 0; r < 2; ++r) {
            const int s0 = sIdxBase - 31 * (kc * 2 + r);
            float4 av;
            av.x = sbl[s0];
            av.y = sbl[s0 + 1];
            av.z = sbl[s0 + 2];
            av.w = sbl[s0 + 3];
            *(float4*)&At[tx + 16 * r][iBase4] = av;
        }
#pragma unroll
        for (int r = 0; r < 2; ++r) {
            const uint32_t wd = vbw[kc * 32 + 16 * r];
            float4 b0, b1;
            b0.x = (float)((wd >> d0S) & 1u);
            b0.y = (float)((wd >> (d0S + 1)) & 1u);
            b0.z = (float)((wd >> (d0S + 2)) & 1u);
            b0.w = (float)((wd >> (d0S + 3)) & 1u);
            b1.x = (float)((wd >> (d0S + 4)) & 1u);
            b1.y = (float)((wd >> (d0S + 5)) & 1u);
            b1.z = (float)((wd >> (d0S + 6)) & 1u);
            b1.w = (float)((wd >> (d0S + 7)) & 1u);
            *(float4*)&Bt[ty + 16 * r][n8] = b0;
            *(float4*)&Bt[ty + 16 * r][n8 + 4] = b1;
        }
        __syncthreads();
#pragma unroll
        for (int cc = 0; cc < 32; ++cc) {
            float a[4], bb[8];
            *(float4*)&a[0] = *(const float4*)&At[cc][ty * 4];
            *(float4*)&bb[0] = *(const float4*)&Bt[cc][tx * 8];
            *(float4*)&bb[4] = *(const float4*)&Bt[cc][tx * 8 + 4];
#pragma unroll
            for (int i = 0; i < 4; ++i)
#pragma unroll
                for (int j = 0; j < 8; ++j) acc[i][j] += a[i] * bb[j];
        }
        __syncthreads();
    }

    float* plane = (tj == 0) ? p0 : (tj == 1) ? p1 : (tj == 2) ? p2 : p3;
    const int nrows = (4 - tj) * 256;
    const int c0 = h * 32 + d0S;
#pragma unroll
    for (int r = 0; r < 4; ++r) {
        const int rowL = dt * 256 + iT * 64 + ty * 4 + r;
        float* dst = &plane[((size_t)bS * nrows + rowL) * 256 + c0];
        float4 s0, s1;
        s0.x = acc[r][0]; s0.y = acc[r][1]; s0.z = acc[r][2]; s0.w = acc[r][3];
        s1.x = acc[r][4]; s1.y = acc[r][5]; s1.z = acc[r][6]; s1.w = acc[r][7];
        *(float4*)&dst[0] = s0;
        *(float4*)&dst[4] = s1;
    }
}

// ---------------------------------------------------------------------------
// K4: fused S1 + bias partials + LIF2 -> bit-packed spikes.
// ---------------------------------------------------------------------------
__global__ __launch_bounds__(256) void k4_lif2(
    const uint32_t* __restrict__ qb, const float* __restrict__ Gf,
    const float* __restrict__ p0, const float* __restrict__ p1,
    const float* __restrict__ p2, const float* __restrict__ p3,
    uint32_t* __restrict__ s2c)
{
    const int c = threadIdx.x;
    const int n = blockIdx.x;
    const int b = blockIdx.y;
    const int lane = c & 63;
    const int h = c >> 5, d = c & 31;
    const int bh = b * NH_ + h;
    const uint32_t* qbh = qb + (size_t)bh * TN_;

    float memv = 0.0f, spk = 0.0f;
    for (int t = 0; t < T_; ++t) {
        const int l = t * N_ + n;
        const uint32_t q = qbh[l];
        const float* g = Gf + (size_t)(bh * 4 + t) * 1024 + d;
        float v = 0.0f;
#pragma unroll
        for (int d2 = 0; d2 < 32; ++d2)
            v += ((q >> d2) & 1u) ? g[d2 * 32] : 0.0f;
        v += p0[((size_t)b * 1024 + l) * 256 + c];
        if (t >= 1) v += p1[((size_t)b * 768 + (l - 256)) * 256 + c];
        if (t >= 2) v += p2[((size_t)b * 512 + (l - 512)) * 256 + c];
        if (t >= 3) v += p3[((size_t)b * 256 + (l - 768)) * 256 + c];
        const float m = (memv - 0.5f * spk) * 0.25f + 0.125f * v;
        memv = m;
        const float s = quant1f(m);
        spk = s;
        const uint64_t mask = __ballot(s != 0.0f);
        if (lane == 0)
            s2c[((size_t)b * TN_ + l) * 8 + (c >> 5)] = (uint32_t)mask;
        else if (lane == 32)
            s2c[((size_t)b * TN_ + l) * 8 + (c >> 5)] = (uint32_t)(mask >> 32);
    }
}

// ---------------------------------------------------------------------------
// K5: fused proj GEMM + bias + BN + final LIF -> writes d_out directly.
// ---------------------------------------------------------------------------
__global__ __launch_bounds__(256) void k5_proj_lif(
    const uint32_t* __restrict__ s2c, const float* __restrict__ w,
    const float* __restrict__ bp,
    const float* __restrict__ gamma, const float* __restrict__ beta,
    const float* __restrict__ mean, const float* __restrict__ var,
    float* __restrict__ out)
{
    __shared__ float At[128][36];    // [k-local][row], 32 rows (+4 pad)
    __shared__ uint32_t Sw[128 * 9]; // [l'][8 words] padded to 9
    const int nBase = blockIdx.x * 32;
    const int oBase = blockIdx.y * 32;
    const int b = blockIdx.z;
    const int tid = threadIdx.x;
    const int tx = tid & 31;   // n = nBase + tx
    const int ty = tid >> 5;   // rows ty*4..+3

#pragma unroll
    for (int j = 0; j < 4; ++j) {
        const int fidx = tid * 4 + j;
        const int lp = fidx >> 3, wsel = fidx & 7;
        const int t = lp >> 5, nn = lp & 31;
        Sw[lp * 9 + wsel] = s2c[((size_t)b * TN_ + t * 256 + nBase + nn) * 8 + wsel];
    }

    const int a_row = tid >> 3, a_kq = (tid & 7) * 16;

    float acc[4][4];
#pragma unroll
    for (int r = 0; r < 4; ++r)
#pragma unroll
        for (int t = 0; t < 4; ++t) acc[r][t] = 0.0f;

    for (int half = 0; half < 2; ++half) {
        if (half) __syncthreads();
#pragma unroll
        for (int j = 0; j < 4; ++j) {
            const float4 v = *(const float4*)&w[(size_t)(oBase + a_row) * C_ + half * 128 + a_kq + 4 * j];
            At[a_kq + 4 * j][a_row] = v.x;
            At[a_kq + 4 * j + 1][a_row] = v.y;
            At[a_kq + 4 * j + 2][a_row] = v.z;
            At[a_kq + 4 * j + 3][a_row] = v.w;
        }
        __syncthreads();

        for (int ks = 0; ks < 4; ++ks) {
            uint32_t wr[4];
#pragma unroll
            for (int t = 0; t < 4; ++t)
                wr[t] = Sw[(t * 32 + tx) * 9 + half * 4 + ks];
#pragma unroll
            for (int u = 0; u < 32; ++u) {
                float a[4];
                *(float4*)&a[0] = *(const float4*)&At[ks * 32 + u][ty * 4];
                float bv[4];
#pragma unroll
                for (int t = 0; t < 4; ++t) bv[t] = (float)((wr[t] >> u) & 1u);
#pragma unroll
                for (int r = 0; r < 4; ++r)
#pragma unroll
                    for (int t = 0; t < 4; ++t) acc[r][t] += a[r] * bv[t];
            }
        }
    }

#pragma unroll
    for (int r = 0; r < 4; ++r) {
        const int o = oBase + ty * 4 + r;
        const float inv = 1.0f / sqrtf(var[o] + 1e-5f);
        const float g = gamma[o] * inv;
        const float mn = mean[o], bt = beta[o], bpo = bp[o];
        float memv = 0.0f, spk = 0.0f;
#pragma unroll
        for (int t = 0; t < 4; ++t) {
            const float val = ((acc[r][t] + bpo) - mn) * g + bt;
            const float m = (memv - 0.5f * spk) * 0.25f + val;
            memv = m;
            const float s = quant1f(m);
            spk = s;
            out[(((size_t)t * B_ + b) * C_ + o) * N_ + nBase + tx] = s;
        }
    }
}

// ---------------------------------------------------------------------------
extern "C" void kernel_launch(void* const* d_in, const int* in_sizes, int n_in,
                              void* d_out, int out_size, void* d_ws, size_t ws_size,
                              hipStream_t stream)
{
    const float* x          = (const float*)d_in[0];
    const float* w_qkv      = (const float*)d_in[1];
    const float* qkv_gamma  = (const float*)d_in[2];
    const float* qkv_beta   = (const float*)d_in[3];
    const float* qkv_mean   = (const float*)d_in[4];
    const float* qkv_var    = (const float*)d_in[5];
    const float* bias_table = (const float*)d_in[6];
    const float* w_proj     = (const float*)d_in[7];
    const float* b_proj     = (const float*)d_in[8];
    const float* proj_gamma = (const float*)d_in[9];
    const float* proj_beta  = (const float*)d_in[10];
    const float* proj_mean  = (const float*)d_in[11];
    const float* proj_var   = (const float*)d_in[12];
    float* out = (float*)d_out;

    // workspace layout (bytes). Gf (1 MiB) lives in the dead qkv_bn region
    // at 25165824, overlap-free with the partial planes (R8's bug).
    char* ws = (char*)d_ws;
    float*    qkv_bn = (float*)(ws + 0);            // 25165824 B (dead after K2)
    float*    part0  = (float*)(ws + 1048576);      //  8388608 B (after K2)
    float*    part1  = (float*)(ws + 9437184);      //  6291456 B
    float*    part2  = (float*)(ws + 15728640);     //  4194304 B
    float*    part3  = (float*)(ws + 19922944);     //  2097152 B (end 22020096)
    float*    Gf     = (float*)(ws + 25165824);     //  1048576 B (end 26214400)
    uint32_t* s2c    = (uint32_t*)(ws + 33554432);  //   262144 B (packed spikes)
    uint32_t* qbits  = (uint32_t*)(ws + 50331648);  //   262144 B
    uint32_t* kbits  = (uint32_t*)(ws + 50593792);
    uint32_t* vbits  = (uint32_t*)(ws + 50855936);  // end 51118080

    k1_qkv_gemm<<<dim3(8, 12, 8), 256, 0, stream>>>(
        x, w_qkv, qkv_gamma, qkv_beta, qkv_mean, qkv_var, qkv_bn);

    k2_lif_pack<<<dim3(24, 8), 256, 0, stream>>>(qkv_bn, qbits, kbits, vbits);

    k3_tg<<<dim3(64), 256, 0, stream>>>(kbits, vbits, Gf);

    k3_bias_gemm<<<dim3(2, 4, 80), 256, 0, stream>>>(
        vbits, bias_table, part0, part1, part2, part3);

    k4_lif2<<<dim3(256, 8), 256, 0, stream>>>(
        qbits, Gf, part0, part1, part2, part3, s2c);

    k5_proj_lif<<<dim3(8, 8, 8), 256, 0, stream>>>(
        s2c, w_proj, b_proj, proj_gamma, proj_beta, proj_mean, proj_var, out);
}

// Round 11
// 223.193 us; speedup vs baseline: 1.1239x; 1.0150x over previous
//
#include <hip/hip_runtime.h>
#include <stdint.h>
#include <math.h>

// Problem constants
constexpr int T_ = 4;
constexpr int B_ = 8;
constexpr int C_ = 256;
constexpr int N_ = 256;          // H*W
constexpr int TN_ = 1024;        // T*N
constexpr int NH_ = 8;           // heads
constexpr int O3_ = 768;         // 3*C
constexpr int BIAS_ROWS_ = 6727; // 7*31*31

__device__ __constant__ int TI_OF[10] = {0,1,1,2,2,2,3,3,3,3};
__device__ __constant__ int TJ_OF[10] = {0,0,1,0,1,2,0,1,2,3};

__device__ __forceinline__ float quant1f(float m) {
    return rintf(fminf(fmaxf(m, 0.0f), 1.0f));
}

// ---------------------------------------------------------------------------
// K1: qkv = BN(w_qkv @ xf)   out[b][o][l]
// 64x128 tile, 8x4 microtile, K-chunk 32 (R10 config, best measured).
// ---------------------------------------------------------------------------
__global__ __launch_bounds__(256) void k1_qkv_gemm(
    const float* __restrict__ x, const float* __restrict__ w,
    const float* __restrict__ gamma, const float* __restrict__ beta,
    const float* __restrict__ mean, const float* __restrict__ var,
    float* __restrict__ out)
{
    __shared__ float At[32][68];   // [k][m], m=64 (+4 pad)
    __shared__ float Bt[32][132];  // [k][n], n=128 (+4 pad)
    const int b = blockIdx.z;
    const int oBase = blockIdx.y * 64;
    const int lBase = blockIdx.x * 128;
    const int tid = threadIdx.x;
    const int tx = tid & 31;        // n: cols tx*4..+3
    const int ty = tid >> 5;        // m: rows {0,32}+ty*4..+3
    const float* xb = x + (size_t)b * C_ * TN_;

    float acc[8][4];
#pragma unroll
    for (int i = 0; i < 8; ++i)
#pragma unroll
        for (int j = 0; j < 4; ++j) acc[i][j] = 0.0f;

    const int a_row0 = tid >> 4, a_k2 = (tid & 15) * 2;
    const int b_kk0 = tid >> 5, b_c4 = (tid & 31) * 4;

    for (int kc = 0; kc < 8; ++kc) {
        const int k0 = kc * 32;
#pragma unroll
        for (int r = 0; r < 4; ++r) {
            const int row = a_row0 + 16 * r;
            const float2 v = *(const float2*)&w[(size_t)(oBase + row) * C_ + k0 + a_k2];
            At[a_k2][row] = v.x;
            At[a_k2 + 1][row] = v.y;
        }
#pragma unroll
        for (int r = 0; r < 4; ++r) {
            const int kk = b_kk0 + 8 * r;
            const float4 v = *(const float4*)&xb[(size_t)(k0 + kk) * TN_ + lBase + b_c4];
            *(float4*)&Bt[kk][b_c4] = v;
        }
        __syncthreads();
#pragma unroll
        for (int cc = 0; cc < 32; ++cc) {
            float a[8], bb[4];
            *(float4*)&a[0] = *(const float4*)&At[cc][ty * 4];
            *(float4*)&a[4] = *(const float4*)&At[cc][32 + ty * 4];
            *(float4*)&bb[0] = *(const float4*)&Bt[cc][tx * 4];
#pragma unroll
            for (int i = 0; i < 8; ++i)
#pragma unroll
                for (int j = 0; j < 4; ++j) acc[i][j] += a[i] * bb[j];
        }
        __syncthreads();
    }

#pragma unroll
    for (int i = 0; i < 8; ++i) {
        const int o = oBase + (i >> 2) * 32 + ty * 4 + (i & 3);
        const float inv = 1.0f / sqrtf(var[o] + 1e-5f);
        const float g = gamma[o] * inv;
        const float mn = mean[o], bt = beta[o];
        float4 st;
        st.x = (acc[i][0] - mn) * g + bt;
        st.y = (acc[i][1] - mn) * g + bt;
        st.z = (acc[i][2] - mn) * g + bt;
        st.w = (acc[i][3] - mn) * g + bt;
        *(float4*)&out[((size_t)b * O3_ + o) * TN_ + lBase + tx * 4] = st;
    }
}

// ---------------------------------------------------------------------------
// K2: LIF over t, pack spikes. Split over d-halves (blockIdx.z): per-d LIF
// recurrences are independent; uint16 half-word stores decouple the pack.
// 384 blocks (2x R10's parallelism), half the serial load chain per thread.
// ---------------------------------------------------------------------------
__global__ __launch_bounds__(256) void k2_lif_pack(
    const float* __restrict__ qkv,
    uint32_t* __restrict__ qb, uint32_t* __restrict__ kb, uint32_t* __restrict__ vb)
{
    const int n = threadIdx.x;
    const int g = blockIdx.x;
    const int b = blockIdx.y;
    const int dh = blockIdx.z;          // 0: d 0..15, 1: d 16..31
    const int which = g >> 3, h = g & 7;
    uint32_t* dstw = (which == 0) ? qb : (which == 1) ? kb : vb;
    uint16_t* dst = (uint16_t*)dstw;
    const float* src = qkv + ((size_t)b * O3_ + g * 32 + dh * 16) * TN_;

    float memv[16];
#pragma unroll
    for (int d = 0; d < 16; ++d) memv[d] = 0.0f;
    uint32_t prev = 0;

    for (int t = 0; t < T_; ++t) {
        uint32_t bits = 0;
#pragma unroll
        for (int d = 0; d < 16; ++d) {
            const float xv = src[(size_t)d * TN_ + t * N_ + n];
            const float m = (memv[d] - 0.5f * (float)((prev >> d) & 1u)) * 0.25f + xv;
            memv[d] = m;
            const float s = quant1f(m);
            bits |= ((uint32_t)s) << d;
        }
        prev = bits;
        dst[2 * (((size_t)b * NH_ + h) * TN_ + t * N_ + n) + dh] = (uint16_t)bits;
    }
}

// ---------------------------------------------------------------------------
// K3tg: fused ballot bit-transpose + cumulative Gram matrix, one block per bh.
// ---------------------------------------------------------------------------
__global__ __launch_bounds__(256) void k3_tg(
    const uint32_t* __restrict__ kb, const uint32_t* __restrict__ vb,
    float* __restrict__ Gf)
{
    __shared__ uint64_t ks[4][32][4];
    __shared__ uint64_t vs[4][32][4];
    const int bh = blockIdx.x;
    const int tid = threadIdx.x;
    const int q = tid >> 6, lane = tid & 63;

#pragma unroll
    for (int t = 0; t < T_; ++t) {
        const int j = t * N_ + q * 64 + lane;
        const uint32_t kw = kb[(size_t)bh * TN_ + j];
        const uint32_t vw = vb[(size_t)bh * TN_ + j];
#pragma unroll
        for (int d = 0; d < 32; ++d) {
            const uint64_t mk = __ballot((kw >> d) & 1u);
            const uint64_t mv = __ballot((vw >> d) & 1u);
            if (lane == 0) { ks[t][d][q] = mk; vs[t][d][q] = mv; }
        }
    }
    __syncthreads();

    const int d = tid & 31;
#pragma unroll
    for (int s = 0; s < 4; ++s) {
        const int d2 = (tid >> 5) + 8 * s;
        int cum = 0;
#pragma unroll
        for (int t = 0; t < T_; ++t) {
            int p = 0;
#pragma unroll
            for (int w = 0; w < 4; ++w) p += __popcll(ks[t][d2][w] & vs[t][d][w]);
            cum += p;
            Gf[(size_t)(bh * 4 + t) * 1024 + d2 * 32 + d] = (float)cum;
        }
    }
}

// ---------------------------------------------------------------------------
// K3gemm: balanced split-K bias GEMM, K-chunk 32.
// Inner B reads restrided to 16B lane stride (cols tx*4 and 64+tx*4) --
// R10's tx*8 (32B stride) reads were 4-way conflicted (5.9M conflicts).
// Ascending-j sum order per output element unchanged (bit-identical).
// ---------------------------------------------------------------------------
__global__ __launch_bounds__(256) void k3_bias_gemm(
    const uint32_t* __restrict__ vb, const float* __restrict__ bias_table,
    float* __restrict__ p0, float* __restrict__ p1,
    float* __restrict__ p2, float* __restrict__ p3)
{
    __shared__ float sbl[640];
    __shared__ float At[32][68];   // [j-in-chunk][i-local]
    __shared__ float Bt[32][132];  // [j-in-chunk][n-local]

    const int z = blockIdx.z;
    const int h = z / 10;
    const int p = z % 10;
    const int ti = TI_OF[p], tj = TJ_OF[p];
    const int dt = ti - tj;
    const int iT = blockIdx.y;
    const int nBase = blockIdx.x * 128;
    const int tid = threadIdx.x;

    const int base = 3363 + 961 * dt + 124 * iT - 480;
    for (int s = tid; s < 640; s += 256) {
        const int gidx = base + s;
        sbl[s] = (gidx < BIAS_ROWS_) ? bias_table[(size_t)gidx * NH_ + h] : 0.0f;
    }

    const int ty = tid >> 4, tx = tid & 15;

    // A-staging: cc = tx + 16r (r=0,1), rows iBase4..+3
    const int iBase4 = ty * 4;
    const int sIdxBase = 31 * (iBase4 >> 4) + (iBase4 & 15) + 480 - tx;

    // B-staging (unchanged): rows kk = ty + 16r, cols tx*8..+7
    const int n8 = tx * 8;
    const int nS = nBase + n8;
    const int bS = nS >> 5, d0S = nS & 31;
    const uint32_t* vbw = vb + ((size_t)bS * NH_ + h) * TN_ + tj * 256 + ty;

    // Compute-column mapping (16B-stride reads): groups at tx*4 and 64+tx*4
    const int nA = nBase + tx * 4;        // cols nA..nA+3   (acc[][0..3])
    const int nB = nBase + 64 + tx * 4;   // cols nB..nB+3   (acc[][4..7])
    const int bA = nA >> 5, dA = nA & 31;
    const int bB = nB >> 5, dB = nB & 31;

    float acc[4][8];
#pragma unroll
    for (int i = 0; i < 4; ++i)
#pragma unroll
        for (int j = 0; j < 8; ++j) acc[i][j] = 0.0f;

    __syncthreads();  // sbl ready

    for (int kc = 0; kc < 8; ++kc) {
#pragma unroll
        for (int r = 0; r < 2; ++r) {
            const int s0 = sIdxBase - 31 * (kc * 2 + r);
            float4 av;
            av.x = sbl[s0];
            av.y = sbl[s0 + 1];
            av.z = sbl[s0 + 2];
            av.w = sbl[s0 + 3];
            *(float4*)&At[tx + 16 * r][iBase4] = av;
        }
#pragma unroll
        for (int r = 0; r < 2; ++r) {
            const uint32_t wd = vbw[kc * 32 + 16 * r];
            float4 b0, b1;
            b0.x = (float)((wd >> d0S) & 1u);
            b0.y = (float)((wd >> (d0S + 1)) & 1u);
            b0.z = (float)((wd >> (d0S + 2)) & 1u);
            b0.w = (float)((wd >> (d0S + 3)) & 1u);
            b1.x = (float)((wd >> (d0S + 4)) & 1u);
            b1.y = (float)((wd >> (d0S + 5)) & 1u);
            b1.z = (float)((wd >> (d0S + 6)) & 1u);
            b1.w = (float)((wd >> (d0S + 7)) & 1u);
            *(float4*)&Bt[ty + 16 * r][n8] = b0;
            *(float4*)&Bt[ty + 16 * r][n8 + 4] = b1;
        }
        __syncthreads();
#pragma unroll
        for (int cc = 0; cc < 32; ++cc) {
            float a[4], bb[8];
            *(float4*)&a[0] = *(const float4*)&At[cc][ty * 4];
            *(float4*)&bb[0] = *(const float4*)&Bt[cc][tx * 4];        // 16B stride
            *(float4*)&bb[4] = *(const float4*)&Bt[cc][64 + tx * 4];   // 16B stride
#pragma unroll
            for (int i = 0; i < 4; ++i)
#pragma unroll
                for (int j = 0; j < 8; ++j) acc[i][j] += a[i] * bb[j];
        }
        __syncthreads();
    }

    float* plane = (tj == 0) ? p0 : (tj == 1) ? p1 : (tj == 2) ? p2 : p3;
    const int nrows = (4 - tj) * 256;
    const int cA = h * 32 + dA;
    const int cB = h * 32 + dB;
#pragma unroll
    for (int r = 0; r < 4; ++r) {
        const int rowL = dt * 256 + iT * 64 + ty * 4 + r;
        float4 s0, s1;
        s0.x = acc[r][0]; s0.y = acc[r][1]; s0.z = acc[r][2]; s0.w = acc[r][3];
        s1.x = acc[r][4]; s1.y = acc[r][5]; s1.z = acc[r][6]; s1.w = acc[r][7];
        *(float4*)&plane[((size_t)bA * nrows + rowL) * 256 + cA] = s0;
        *(float4*)&plane[((size_t)bB * nrows + rowL) * 256 + cB] = s1;
    }
}

// ---------------------------------------------------------------------------
// K4: fused S1 + bias partials + LIF2 -> bit-packed spikes.
// ---------------------------------------------------------------------------
__global__ __launch_bounds__(256) void k4_lif2(
    const uint32_t* __restrict__ qb, const float* __restrict__ Gf,
    const float* __restrict__ p0, const float* __restrict__ p1,
    const float* __restrict__ p2, const float* __restrict__ p3,
    uint32_t* __restrict__ s2c)
{
    const int c = threadIdx.x;
    const int n = blockIdx.x;
    const int b = blockIdx.y;
    const int lane = c & 63;
    const int h = c >> 5, d = c & 31;
    const int bh = b * NH_ + h;
    const uint32_t* qbh = qb + (size_t)bh * TN_;

    float memv = 0.0f, spk = 0.0f;
    for (int t = 0; t < T_; ++t) {
        const int l = t * N_ + n;
        const uint32_t q = qbh[l];
        const float* g = Gf + (size_t)(bh * 4 + t) * 1024 + d;
        float v = 0.0f;
#pragma unroll
        for (int d2 = 0; d2 < 32; ++d2)
            v += ((q >> d2) & 1u) ? g[d2 * 32] : 0.0f;
        v += p0[((size_t)b * 1024 + l) * 256 + c];
        if (t >= 1) v += p1[((size_t)b * 768 + (l - 256)) * 256 + c];
        if (t >= 2) v += p2[((size_t)b * 512 + (l - 512)) * 256 + c];
        if (t >= 3) v += p3[((size_t)b * 256 + (l - 768)) * 256 + c];
        const float m = (memv - 0.5f * spk) * 0.25f + 0.125f * v;
        memv = m;
        const float s = quant1f(m);
        spk = s;
        const uint64_t mask = __ballot(s != 0.0f);
        if (lane == 0)
            s2c[((size_t)b * TN_ + l) * 8 + (c >> 5)] = (uint32_t)mask;
        else if (lane == 32)
            s2c[((size_t)b * TN_ + l) * 8 + (c >> 5)] = (uint32_t)(mask >> 32);
    }
}

// ---------------------------------------------------------------------------
// K5: fused proj GEMM + bias + BN + final LIF -> writes d_out directly.
// ---------------------------------------------------------------------------
__global__ __launch_bounds__(256) void k5_proj_lif(
    const uint32_t* __restrict__ s2c, const float* __restrict__ w,
    const float* __restrict__ bp,
    const float* __restrict__ gamma, const float* __restrict__ beta,
    const float* __restrict__ mean, const float* __restrict__ var,
    float* __restrict__ out)
{
    __shared__ float At[128][36];    // [k-local][row], 32 rows (+4 pad)
    __shared__ uint32_t Sw[128 * 9]; // [l'][8 words] padded to 9
    const int nBase = blockIdx.x * 32;
    const int oBase = blockIdx.y * 32;
    const int b = blockIdx.z;
    const int tid = threadIdx.x;
    const int tx = tid & 31;   // n = nBase + tx
    const int ty = tid >> 5;   // rows ty*4..+3

#pragma unroll
    for (int j = 0; j < 4; ++j) {
        const int fidx = tid * 4 + j;
        const int lp = fidx >> 3, wsel = fidx & 7;
        const int t = lp >> 5, nn = lp & 31;
        Sw[lp * 9 + wsel] = s2c[((size_t)b * TN_ + t * 256 + nBase + nn) * 8 + wsel];
    }

    const int a_row = tid >> 3, a_kq = (tid & 7) * 16;

    float acc[4][4];
#pragma unroll
    for (int r = 0; r < 4; ++r)
#pragma unroll
        for (int t = 0; t < 4; ++t) acc[r][t] = 0.0f;

    for (int half = 0; half < 2; ++half) {
        if (half) __syncthreads();
#pragma unroll
        for (int j = 0; j < 4; ++j) {
            const float4 v = *(const float4*)&w[(size_t)(oBase + a_row) * C_ + half * 128 + a_kq + 4 * j];
            At[a_kq + 4 * j][a_row] = v.x;
            At[a_kq + 4 * j + 1][a_row] = v.y;
            At[a_kq + 4 * j + 2][a_row] = v.z;
            At[a_kq + 4 * j + 3][a_row] = v.w;
        }
        __syncthreads();

        for (int ks = 0; ks < 4; ++ks) {
            uint32_t wr[4];
#pragma unroll
            for (int t = 0; t < 4; ++t)
                wr[t] = Sw[(t * 32 + tx) * 9 + half * 4 + ks];
#pragma unroll
            for (int u = 0; u < 32; ++u) {
                float a[4];
                *(float4*)&a[0] = *(const float4*)&At[ks * 32 + u][ty * 4];
                float bv[4];
#pragma unroll
                for (int t = 0; t < 4; ++t) bv[t] = (float)((wr[t] >> u) & 1u);
#pragma unroll
                for (int r = 0; r < 4; ++r)
#pragma unroll
                    for (int t = 0; t < 4; ++t) acc[r][t] += a[r] * bv[t];
            }
        }
    }

#pragma unroll
    for (int r = 0; r < 4; ++r) {
        const int o = oBase + ty * 4 + r;
        const float inv = 1.0f / sqrtf(var[o] + 1e-5f);
        const float g = gamma[o] * inv;
        const float mn = mean[o], bt = beta[o], bpo = bp[o];
        float memv = 0.0f, spk = 0.0f;
#pragma unroll
        for (int t = 0; t < 4; ++t) {
            const float val = ((acc[r][t] + bpo) - mn) * g + bt;
            const float m = (memv - 0.5f * spk) * 0.25f + val;
            memv = m;
            const float s = quant1f(m);
            spk = s;
            out[(((size_t)t * B_ + b) * C_ + o) * N_ + nBase + tx] = s;
        }
    }
}

// ---------------------------------------------------------------------------
extern "C" void kernel_launch(void* const* d_in, const int* in_sizes, int n_in,
                              void* d_out, int out_size, void* d_ws, size_t ws_size,
                              hipStream_t stream)
{
    const float* x          = (const float*)d_in[0];
    const float* w_qkv      = (const float*)d_in[1];
    const float* qkv_gamma  = (const float*)d_in[2];
    const float* qkv_beta   = (const float*)d_in[3];
    const float* qkv_mean   = (const float*)d_in[4];
    const float* qkv_var    = (const float*)d_in[5];
    const float* bias_table = (const float*)d_in[6];
    const float* w_proj     = (const float*)d_in[7];
    const float* b_proj     = (const float*)d_in[8];
    const float* proj_gamma = (const float*)d_in[9];
    const float* proj_beta  = (const float*)d_in[10];
    const float* proj_mean  = (const float*)d_in[11];
    const float* proj_var   = (const float*)d_in[12];
    float* out = (float*)d_out;

    // workspace layout (bytes). Gf (1 MiB) in dead qkv_bn region, overlap-free.
    char* ws = (char*)d_ws;
    float*    qkv_bn = (float*)(ws + 0);            // 25165824 B (dead after K2)
    float*    part0  = (float*)(ws + 1048576);      //  8388608 B (after K2)
    float*    part1  = (float*)(ws + 9437184);      //  6291456 B
    float*    part2  = (float*)(ws + 15728640);     //  4194304 B
    float*    part3  = (float*)(ws + 19922944);     //  2097152 B (end 22020096)
    float*    Gf     = (float*)(ws + 25165824);     //  1048576 B (end 26214400)
    uint32_t* s2c    = (uint32_t*)(ws + 33554432);  //   262144 B (packed spikes)
    uint32_t* qbits  = (uint32_t*)(ws + 50331648);  //   262144 B
    uint32_t* kbits  = (uint32_t*)(ws + 50593792);
    uint32_t* vbits  = (uint32_t*)(ws + 50855936);  // end 51118080

    k1_qkv_gemm<<<dim3(8, 12, 8), 256, 0, stream>>>(
        x, w_qkv, qkv_gamma, qkv_beta, qkv_mean, qkv_var, qkv_bn);

    k2_lif_pack<<<dim3(24, 8, 2), 256, 0, stream>>>(qkv_bn, qbits, kbits, vbits);

    k3_tg<<<dim3(64), 256, 0, stream>>>(kbits, vbits, Gf);

    k3_bias_gemm<<<dim3(2, 4, 80), 256, 0, stream>>>(
        vbits, bias_table, part0, part1, part2, part3);

    k4_lif2<<<dim3(256, 8), 256, 0, stream>>>(
        qbits, Gf, part0, part1, part2, part3, s2c);

    k5_proj_lif<<<dim3(8, 8, 8), 256, 0, stream>>>(
        s2c, w_proj, b_proj, proj_gamma, proj_beta, proj_mean, proj_var, out);
}